// Round 7
// baseline (607.625 us; speedup 1.0000x reference)
//
#include <hip/hip_runtime.h>
#include <hip/hip_bf16.h>
#include <stdint.h>

typedef __attribute__((ext_vector_type(4))) float f32x4;
typedef __attribute__((ext_vector_type(8))) short short8;
typedef unsigned int u32;
typedef unsigned short ushort_t;

#define L_DIM 2048
#define B_DIM 32
#define D_DIM 512
#define M_DIM (L_DIM * B_DIM)       // 65536
#define N_DIM (3 * D_DIM)           // 1536
#define K_DIM D_DIM                 // 512
#define BD    (B_DIM * D_DIM)       // 16384
#define PLANE ((size_t)M_DIM * D_DIM)  // 33554432 elems per U plane
#define CHUNK 32
#define NCHUNK (L_DIM / CHUNK)      // 64
#define CNT_OFF 270008320           // byte offset of strip counters in ws

// ---------- helpers ----------
__device__ inline ushort_t f2bf(float f) {
    uint32_t u = __float_as_uint(f);
    u += 0x7FFFu + ((u >> 16) & 1u);   // RNE
    return (ushort_t)(u >> 16);
}
__device__ inline float b2f(ushort_t h) {
    return __uint_as_float(((uint32_t)h) << 16);
}
__device__ inline void gll16(const ushort_t* g, ushort_t* l) {
    __builtin_amdgcn_global_load_lds(
        (const __attribute__((address_space(1))) u32*)g,
        (__attribute__((address_space(3))) u32*)l,
        16, 0, 0);
}

// ---------- kernel 1: x (f32) -> xb (bf16) ----------
__global__ void k_convert_x(const float4* __restrict__ x, ushort4* __restrict__ xb) {
    int i = blockIdx.x * blockDim.x + threadIdx.x;
    int stride = gridDim.x * blockDim.x;
    const int n4 = M_DIM * D_DIM / 4;   // 8388608
    for (; i < n4; i += stride) {
        float4 v = x[i];
        ushort4 o;
        o.x = f2bf(v.x); o.y = f2bf(v.y); o.z = f2bf(v.z); o.w = f2bf(v.w);
        xb[i] = o;
    }
}

// ---------- kernel 2: weight (D,3D) f32 -> wt [N][K] bf16, gate-deinterleaved ----------
__global__ void k_prep_w(const float* __restrict__ w, ushort_t* __restrict__ wt) {
    int idx = blockIdx.x * blockDim.x + threadIdx.x;
    if (idx >= N_DIM * K_DIM) return;
    int k = idx & 511;
    int n = idx >> 9;
    int dcol = (n & 511) * 3 + (n >> 9);
    wt[idx] = f2bf(w[(size_t)k * N_DIM + dcol]);
}

// ---------- fused kernel: persistent GEMM + overlapped sequential scan ----------
// 768 blocks x 256 thr, 32 KB LDS, ~3 blocks/CU (all resident).
// blocks 0..255:  4 GEMM tiles, then scan 64 chains (producer/consumer waves).
// blocks 256..767: 10 GEMM tiles.
// Tile order: iteration j covers tiles j*768+q (early, all blocks, j<4) then
// 3072 + j2*512 + (q-256) (late) -> strips complete in ascending order.
// Per-strip counter (12 tiles each) released agent-scope; scan spins relaxed.
__global__ __launch_bounds__(256) void k_fused(
    const ushort_t* __restrict__ Ag,   // xb [M,K] bf16 (also scan x)
    const ushort_t* __restrict__ Wt,   // [N,K] bf16
    const float*    __restrict__ bias, // [2D]
    ushort_t*       __restrict__ U,    // 3 planes of [M,D] bf16
    const float*    __restrict__ wc,   // weight_c [2D]
    const float*    __restrict__ cin,  // c_init [B,D]
    float*          __restrict__ out,  // h [L,B,D] f32 then c_last [B,D]
    u32*            __restrict__ cnt)  // [512] strip completion counters
{
    __shared__ ushort_t smem[16384];   // 32 KB: GEMM As|Bs, later scan ring
    ushort_t* As = smem;
    ushort_t* Bs = smem + 8192;

    const int tid  = threadIdx.x;
    const int lane = tid & 63;
    const int wv   = tid >> 6;
    const int wm   = wv >> 1, wn = wv & 1;
    const int hw   = blockIdx.x;

    // XCD-chunked slot remap (hw&7 = XCD under round-robin dispatch)
    int q;
    if (hw < 256) q = (hw & 7) * 32 + (hw >> 3);
    else { int h2 = hw - 256; q = 256 + (h2 & 7) * 64 + (h2 >> 3); }

#define GEMM_TILE(T)                                                           \
    {                                                                          \
        const int bx  = (T) % 12;                                              \
        const int by  = (T) / 12;                                              \
        const int bn0 = bx * 128;                                              \
        const int bm0 = by * 128;                                              \
        f32x4 acc[4][4] = {};                                                  \
        for (int kt = 0; kt < K_DIM / 64; ++kt) {                              \
            if (kt) __syncthreads();                                           \
            _Pragma("unroll")                                                  \
            for (int it = 0; it < 4; ++it) {                                   \
                int c_   = it * 256 + tid;                                     \
                int row  = c_ >> 3;                                            \
                int cin_ = (c_ & 7) ^ (row & 7);                               \
                const ushort_t* ga = Ag + (size_t)(bm0 + row) * K_DIM          \
                                     + kt * 64 + cin_ * 8;                     \
                const ushort_t* gb = Wt + (size_t)(bn0 + row) * K_DIM          \
                                     + kt * 64 + cin_ * 8;                     \
                int chunkbase = it * 256 + wv * 64;                            \
                gll16(ga, As + chunkbase * 8);                                 \
                gll16(gb, Bs + chunkbase * 8);                                 \
            }                                                                  \
            __syncthreads();                                                   \
            _Pragma("unroll")                                                  \
            for (int kk = 0; kk < 2; ++kk) {                                   \
                short8 af[4], bfr[4];                                          \
                _Pragma("unroll")                                              \
                for (int m = 0; m < 4; ++m) {                                  \
                    int row  = wm * 64 + m * 16 + (lane & 15);                 \
                    int byte = (row * 128 + kk * 64 + ((lane >> 4) * 16))      \
                               ^ ((row & 7) << 4);                             \
                    af[m] = *(const short8*)((const char*)As + byte);          \
                }                                                              \
                _Pragma("unroll")                                              \
                for (int n = 0; n < 4; ++n) {                                  \
                    int row  = wn * 64 + n * 16 + (lane & 15);                 \
                    int byte = (row * 128 + kk * 64 + ((lane >> 4) * 16))      \
                               ^ ((row & 7) << 4);                             \
                    bfr[n] = *(const short8*)((const char*)Bs + byte);         \
                }                                                              \
                _Pragma("unroll")                                              \
                for (int m = 0; m < 4; ++m)                                    \
                    _Pragma("unroll")                                          \
                    for (int n = 0; n < 4; ++n)                                \
                        acc[m][n] = __builtin_amdgcn_mfma_f32_16x16x32_bf16(   \
                            af[m], bfr[n], acc[m][n], 0, 0, 0);                \
            }                                                                  \
        }                                                                      \
        const int g_  = bn0 >> 9;                                              \
        const int db  = (bn0 & 511) + wn * 64;                                 \
        ushort_t* Up  = U + (size_t)g_ * PLANE;                                \
        _Pragma("unroll")                                                      \
        for (int n = 0; n < 4; ++n) {                                          \
            int col = db + n * 16 + (lane & 15);                               \
            float ba = 0.f;                                                    \
            if (g_) ba = bias[(g_ - 1) * 512 + col];                           \
            _Pragma("unroll")                                                  \
            for (int m = 0; m < 4; ++m) {                                      \
                int row0 = bm0 + wm * 64 + m * 16 + ((lane >> 4) * 4);         \
                _Pragma("unroll")                                              \
                for (int qq = 0; qq < 4; ++qq)                                 \
                    Up[(size_t)(row0 + qq) * D_DIM + col] =                    \
                        f2bf(acc[m][n][qq] + ba);                              \
            }                                                                  \
        }                                                                      \
        __syncthreads();   /* all stores drained (vmcnt0) before release */    \
        if (tid == 0)                                                          \
            __hip_atomic_fetch_add(&cnt[by], 1u, __ATOMIC_RELEASE,             \
                                   __HIP_MEMORY_SCOPE_AGENT);                  \
    }

    // ---- early phase: all 768 blocks, 4 iterations (strips 0..255) ----
    for (int j = 0; j < 4; ++j) GEMM_TILE(j * 768 + q);

    if (hw >= 256) {
        // ---- late phase: gemm-only blocks, 6 iterations (strips 256..511) ----
        const int qq = q - 256;
        for (int j2 = 0; j2 < 6; ++j2) GEMM_TILE(3072 + j2 * 512 + qq);
        return;
    }

    // =================== scan phase (blocks 0..255) ===================
    const int cb = hw * 64;                      // chain base
#define RING(P, NB, ROW) (smem + (((P) * 2 + (NB)) * 2048 + (ROW) * 64))

    // producer (wave 0): gll16 lane l covers step l>>3, chains (l&7)*8
    const int srow = lane >> 3;
    const int scol = (lane & 7) * 8;
    const ushort_t* s0 = U + cb + scol;
    const ushort_t* s1 = U + PLANE + cb + scol;
    const ushort_t* s2 = U + 2 * PLANE + cb + scol;
    const ushort_t* s3 = Ag + cb + scol;

    // consumer (wave 1)
    const int chain = cb + lane;
    const int d     = chain & 511;
    float fw = 0.f, rw = 0.f, c = 0.f;
    if (wv == 1) { fw = wc[d]; rw = wc[512 + d]; c = cin[chain]; }
    float* ho = out + chain;

#define WAITCHUNK(CK)                                                          \
    if (lane < 8) {                                                            \
        while (__hip_atomic_load(&cnt[(CK) * 8 + lane], __ATOMIC_RELAXED,      \
                                 __HIP_MEMORY_SCOPE_AGENT) < 12u)              \
            __builtin_amdgcn_s_sleep(2);                                       \
    }

#define PRODUCE(CK, NB)                                                        \
    do {                                                                       \
        const size_t t0_ = (size_t)(CK) * CHUNK + srow;                        \
        _Pragma("unroll")                                                      \
        for (int qg = 0; qg < 4; ++qg) {                                       \
            gll16(s0 + (t0_ + qg * 8) * BD, RING(0, NB, qg * 8));              \
            gll16(s1 + (t0_ + qg * 8) * BD, RING(1, NB, qg * 8));              \
            gll16(s2 + (t0_ + qg * 8) * BD, RING(2, NB, qg * 8));              \
            gll16(s3 + (t0_ + qg * 8) * BD, RING(3, NB, qg * 8));              \
        }                                                                      \
    } while (0)

#define LG(P, BUF, g0)                                                         \
    {                                                                          \
        _Pragma("unroll")                                                      \
        for (int s = 0; s < 8; ++s) {                                          \
            P##0[s] = RING(0, BUF, (g0) + s)[lane];                            \
            P##1[s] = RING(1, BUF, (g0) + s)[lane];                            \
            P##2[s] = RING(2, BUF, (g0) + s)[lane];                            \
            P##x[s] = RING(3, BUF, (g0) + s)[lane];                            \
        }                                                                      \
    }

#define CG(P, tb, g0)                                                          \
    {                                                                          \
        _Pragma("unroll")                                                      \
        for (int s = 0; s < 8; ++s) {                                          \
            float u0 = b2f(P##0[s]), u1 = b2f(P##1[s]);                        \
            float u2 = b2f(P##2[s]), xf = b2f(P##x[s]);                        \
            float f = __builtin_amdgcn_rcpf(1.f + __expf(-(u1 + c * fw)));     \
            float r = __builtin_amdgcn_rcpf(1.f + __expf(-(u2 + c * rw)));     \
            c = u0 + (c - u0) * f;                                             \
            ho[(size_t)((tb) + (g0) + s) * BD] = xf + (c - xf) * r;            \
        }                                                                      \
    }

    if (wv == 0) { WAITCHUNK(0); PRODUCE(0, 0); }
    __syncthreads();

    for (int ck = 0; ck < NCHUNK; ++ck) {
        if (wv == 0) {
            if (ck + 1 < NCHUNK) {
                const int nb = (ck + 1) & 1;
                WAITCHUNK(ck + 1);
                PRODUCE(ck + 1, nb);
            }
        } else if (wv == 1) {
            const int buf = ck & 1;
            const int tb  = ck * CHUNK;
            ushort_t A0[8], A1[8], A2[8], Ax[8];
            ushort_t B0[8], B1[8], B2[8], Bx[8];
            LG(A, buf, 0);
            LG(B, buf, 8);
            CG(A, tb, 0);
            LG(A, buf, 16);
            CG(B, tb, 8);
            LG(B, buf, 24);
            CG(A, tb, 16);
            CG(B, tb, 24);
        }
        __syncthreads();
    }

    if (wv == 1) out[(size_t)L_DIM * BD + chain] = c;
}

// ---------- launch ----------
extern "C" void kernel_launch(void* const* d_in, const int* in_sizes, int n_in,
                              void* d_out, int out_size, void* d_ws, size_t ws_size,
                              hipStream_t stream) {
    const float* x      = (const float*)d_in[0];
    const float* weight = (const float*)d_in[1];
    const float* wc     = (const float*)d_in[2];
    const float* bias   = (const float*)d_in[3];
    const float* cinit  = (const float*)d_in[4];
    float* out = (float*)d_out;

    // ws layout (bf16 elems): xb[PLANE] | U0|U1|U2 [3*PLANE] | wt[786432] | cnt
    ushort_t* ws = (ushort_t*)d_ws;
    ushort_t* xb = ws;
    ushort_t* U  = ws + PLANE;           // 3 contiguous planes
    ushort_t* wt = ws + 4 * PLANE;
    u32* cnt = (u32*)((char*)d_ws + CNT_OFF);

    hipMemsetAsync(cnt, 0, 512 * sizeof(u32), stream);
    k_convert_x<<<4096, 256, 0, stream>>>((const float4*)x, (ushort4*)xb);
    k_prep_w<<<(N_DIM * K_DIM) / 256, 256, 0, stream>>>(weight, wt);
    k_fused<<<768, 256, 0, stream>>>(xb, wt, bias, U, wc, cinit, out, cnt);
}

// Round 8
// 453.967 us; speedup vs baseline: 1.3385x; 1.3385x over previous
//
#include <hip/hip_runtime.h>
#include <hip/hip_bf16.h>
#include <stdint.h>

typedef __attribute__((ext_vector_type(4))) float f32x4;
typedef __attribute__((ext_vector_type(8))) short short8;
typedef unsigned int u32;
typedef unsigned short ushort_t;

#define L_DIM 2048
#define B_DIM 32
#define D_DIM 512
#define M_DIM (L_DIM * B_DIM)       // 65536
#define N_DIM (3 * D_DIM)           // 1536
#define K_DIM D_DIM                 // 512
#define BD    (B_DIM * D_DIM)       // 16384
#define PLANE ((size_t)M_DIM * D_DIM)  // 33554432 elems per U plane
#define CHUNK 32
#define NCHUNK (L_DIM / CHUNK)      // 64

// ---------- helpers ----------
__device__ inline ushort_t f2bf(float f) {
    uint32_t u = __float_as_uint(f);
    u += 0x7FFFu + ((u >> 16) & 1u);   // RNE
    return (ushort_t)(u >> 16);
}
__device__ inline float b2f(ushort_t h) {
    return __uint_as_float(((uint32_t)h) << 16);
}
__device__ inline void gll16(const ushort_t* g, ushort_t* l) {
    __builtin_amdgcn_global_load_lds(
        (const __attribute__((address_space(1))) u32*)g,
        (__attribute__((address_space(3))) u32*)l,
        16, 0, 0);
}

// ---------- kernel 1: x (f32) -> xb (bf16) ----------
__global__ void k_convert_x(const float4* __restrict__ x, ushort4* __restrict__ xb) {
    int i = blockIdx.x * blockDim.x + threadIdx.x;
    int stride = gridDim.x * blockDim.x;
    const int n4 = M_DIM * D_DIM / 4;   // 8388608
    for (; i < n4; i += stride) {
        float4 v = x[i];
        ushort4 o;
        o.x = f2bf(v.x); o.y = f2bf(v.y); o.z = f2bf(v.z); o.w = f2bf(v.w);
        xb[i] = o;
    }
}

// ---------- kernel 2: weight (D,3D) f32 -> wt [N][K] bf16, gate-deinterleaved ----------
__global__ void k_prep_w(const float* __restrict__ w, ushort_t* __restrict__ wt) {
    int idx = blockIdx.x * blockDim.x + threadIdx.x;
    if (idx >= N_DIM * K_DIM) return;
    int k = idx & 511;
    int n = idx >> 9;
    int dcol = (n & 511) * 3 + (n >> 9);
    wt[idx] = f2bf(w[(size_t)k * N_DIM + dcol]);
}

// ---------- kernel 3: 256x256 GEMM, 4 waves (128x128 each), BK=32 ----------
// 16x16x32 MFMA, acc f32x4[8][8]=256 VGPR, 1 block/CU (4 waves).
// 3 LDS buffers (96 KB), prefetch depth 2, ONE counted vmcnt(8)+barrier / K-tile.
// LDS virtual layout: tile [256 rows][32 k] stored as [128 vrows][64 elems];
// vrow=row>>1, slot = ((row&1)<<2 | k>>3) ^ (vrow&7)  (proven XOR family).
__global__ __launch_bounds__(256, 1) void k_gemm256(
    const ushort_t* __restrict__ Ag,   // [M,K] bf16
    const ushort_t* __restrict__ Wt,   // [N,K] bf16
    const float*    __restrict__ bias, // [2D]
    ushort_t*       __restrict__ U)    // 3 planes of [M,D] bf16
{
    __shared__ ushort_t As[3][256 * 32];   // 48 KB
    __shared__ ushort_t Bs[3][256 * 32];   // 48 KB
    const int tid  = threadIdx.x;
    const int lane = tid & 63;
    const int wv   = tid >> 6;
    const int wm   = wv >> 1, wn = wv & 1;

    // XCD-chunked swizzle: 1536 blocks, 8 XCDs, 192/XCD (bijective); bx innermost
    const int i   = blockIdx.x;
    const int nb  = (i & 7) * 192 + (i >> 3);
    const int bx  = nb % 6;
    const int by  = nb / 6;
    const int bn0 = bx * 256;
    const int bm0 = by * 256;

    // staging invariants (per round r in 0..3, chunk c = r*256+tid):
    //   vrow = r*32 + (tid>>3); lds slot = tid&7
    //   logical slot sl = (tid&7) ^ (vrow&7)   [vrow&7 == (tid>>3)&7, r-indep]
    //   source row = vrow*2 + (sl>>2) = r*64 + (tid>>3)*2 + (sl>>2);  k = (sl&3)*8
    const int sl     = (tid & 7) ^ ((tid >> 3) & 7);
    const int rowoff = ((tid >> 3) << 1) + (sl >> 2);
    const int kel    = (sl & 3) * 8;
    const ushort_t* pA = Ag + (size_t)(bm0 + rowoff) * K_DIM + kel;
    const ushort_t* pB = Wt + (size_t)(bn0 + rowoff) * K_DIM + kel;

    f32x4 acc[8][8] = {};

#define STAGE(KT, BUF)                                                         \
    {                                                                          \
        ushort_t* Asn = &As[BUF][0];                                           \
        ushort_t* Bsn = &Bs[BUF][0];                                           \
        _Pragma("unroll")                                                      \
        for (int r = 0; r < 4; ++r)                                            \
            gll16(pA + (size_t)(r * 64) * K_DIM + (KT) * 32,                   \
                  Asn + (r * 256 + wv * 64) * 8);                              \
        _Pragma("unroll")                                                      \
        for (int r = 0; r < 4; ++r)                                            \
            gll16(pB + (size_t)(r * 64) * K_DIM + (KT) * 32,                   \
                  Bsn + (r * 256 + wv * 64) * 8);                              \
    }

    // prologue: stage K-tiles 0,1; wait tile 0 (8 of 16 outstanding); barrier
    STAGE(0, 0);
    STAGE(1, 1);
    asm volatile("s_waitcnt vmcnt(8)" ::: "memory");
    __builtin_amdgcn_s_barrier();

    int buf = 0;
    for (int kt = 0; kt < 16; ++kt) {
        const int sbuf = (buf + 2 >= 3) ? buf - 1 : buf + 2;
        if (kt < 14) STAGE(kt + 2, sbuf);

        const ushort_t* Asb = &As[buf][0];
        const ushort_t* Bsb = &Bs[buf][0];
        short8 af[8], bfr[8];
#pragma unroll
        for (int m = 0; m < 8; ++m) {
            int row  = wm * 128 + m * 16 + (lane & 15);
            int vrow = row >> 1;
            int byte = vrow * 128 +
                ((((row & 1) << 2) | (lane >> 4)) ^ (vrow & 7)) * 16;
            af[m] = *(const short8*)((const char*)Asb + byte);
        }
#pragma unroll
        for (int n = 0; n < 8; ++n) {
            int row  = wn * 128 + n * 16 + (lane & 15);
            int vrow = row >> 1;
            int byte = vrow * 128 +
                ((((row & 1) << 2) | (lane >> 4)) ^ (vrow & 7)) * 16;
            bfr[n] = *(const short8*)((const char*)Bsb + byte);
        }
        __builtin_amdgcn_s_setprio(1);
#pragma unroll
        for (int m = 0; m < 8; ++m)
#pragma unroll
            for (int n = 0; n < 8; ++n)
                acc[m][n] = __builtin_amdgcn_mfma_f32_16x16x32_bf16(
                    af[m], bfr[n], acc[m][n], 0, 0, 0);
        __builtin_amdgcn_s_setprio(0);

        if (kt < 14)      asm volatile("s_waitcnt vmcnt(8)" ::: "memory");
        else if (kt == 14) asm volatile("s_waitcnt vmcnt(0)" ::: "memory");
        if (kt < 15) __builtin_amdgcn_s_barrier();

        buf = (buf + 1 >= 3) ? 0 : buf + 1;
    }

#undef STAGE

    // epilogue: C/D layout col=lane&15, row=(lane>>4)*4+q (m89-verified)
    const int g  = bn0 >> 9;               // plane (256-tile never crosses plane)
    ushort_t* Up = U + (size_t)g * PLANE;
#pragma unroll
    for (int n = 0; n < 8; ++n) {
        int col = (bn0 & 511) + wn * 128 + n * 16 + (lane & 15);
        float ba = 0.f;
        if (g) ba = bias[(g - 1) * 512 + col];
#pragma unroll
        for (int m = 0; m < 8; ++m) {
            int row0 = bm0 + wm * 128 + m * 16 + ((lane >> 4) * 4);
#pragma unroll
            for (int q = 0; q < 4; ++q) {
                Up[(size_t)(row0 + q) * D_DIM + col] = f2bf(acc[m][n][q] + ba);
            }
        }
    }
}

// ---------- kernel 4: producer/consumer sequential scan (round-4 verified) ----------
__global__ __launch_bounds__(128) void k_scan(
    const ushort_t* __restrict__ U,    // 3 planes [t*32+b][d]
    const ushort_t* __restrict__ xb,   // [t*32+b][d]
    const float*    __restrict__ wc,   // weight_c [2D]
    const float*    __restrict__ cin,  // c_init [B,D]
    float*          __restrict__ out)  // h [L,B,D] f32, then c_last [B,D]
{
    __shared__ ushort_t ring[4][2][CHUNK][64];   // 32 KiB

    const int tid  = threadIdx.x;
    const int lane = tid & 63;
    const int wid  = tid >> 6;
    const int cb   = blockIdx.x * 64;            // chain base

    const int srow = lane >> 3;
    const int scol = (lane & 7) * 8;
    const ushort_t* s0 = U + cb + scol;
    const ushort_t* s1 = U + PLANE + cb + scol;
    const ushort_t* s2 = U + 2 * PLANE + cb + scol;
    const ushort_t* s3 = xb + cb + scol;

    const int chain = cb + lane;
    const int d     = chain & 511;
    float fw = 0.f, rw = 0.f, c = 0.f;
    if (wid == 1) { fw = wc[d]; rw = wc[512 + d]; c = cin[chain]; }
    float* ho = out + chain;

#define PRODUCE(CK, NB)                                                        \
    do {                                                                       \
        const size_t t0_ = (size_t)(CK) * CHUNK + srow;                        \
        _Pragma("unroll")                                                      \
        for (int q = 0; q < 4; ++q) {                                          \
            gll16(s0 + (t0_ + q * 8) * BD, &ring[0][NB][q * 8][0]);            \
            gll16(s1 + (t0_ + q * 8) * BD, &ring[1][NB][q * 8][0]);            \
            gll16(s2 + (t0_ + q * 8) * BD, &ring[2][NB][q * 8][0]);            \
            gll16(s3 + (t0_ + q * 8) * BD, &ring[3][NB][q * 8][0]);            \
        }                                                                      \
    } while (0)

#define LG(P, BUF, g0)                                                         \
    {                                                                          \
        _Pragma("unroll")                                                      \
        for (int s = 0; s < 8; ++s) {                                          \
            P##0[s] = ring[0][BUF][(g0) + s][lane];                            \
            P##1[s] = ring[1][BUF][(g0) + s][lane];                            \
            P##2[s] = ring[2][BUF][(g0) + s][lane];                            \
            P##x[s] = ring[3][BUF][(g0) + s][lane];                            \
        }                                                                      \
    }

#define CG(P, tb, g0)                                                          \
    {                                                                          \
        _Pragma("unroll")                                                      \
        for (int s = 0; s < 8; ++s) {                                          \
            float u0 = b2f(P##0[s]), u1 = b2f(P##1[s]);                        \
            float u2 = b2f(P##2[s]), xf = b2f(P##x[s]);                        \
            float f = __builtin_amdgcn_rcpf(1.f + __expf(-(u1 + c * fw)));     \
            float r = __builtin_amdgcn_rcpf(1.f + __expf(-(u2 + c * rw)));     \
            c = u0 + (c - u0) * f;                                             \
            ho[(size_t)((tb) + (g0) + s) * BD] = xf + (c - xf) * r;            \
        }                                                                      \
    }

    if (wid == 0) PRODUCE(0, 0);
    __syncthreads();

    for (int ck = 0; ck < NCHUNK; ++ck) {
        if (wid == 0) {
            if (ck + 1 < NCHUNK) {
                const int nb = (ck + 1) & 1;
                PRODUCE(ck + 1, nb);
            }
        } else {
            const int buf = ck & 1;
            const int tb  = ck * CHUNK;
            ushort_t A0[8], A1[8], A2[8], Ax[8];
            ushort_t B0[8], B1[8], B2[8], Bx[8];
            LG(A, buf, 0);
            LG(B, buf, 8);
            CG(A, tb, 0);
            LG(A, buf, 16);
            CG(B, tb, 8);
            LG(B, buf, 24);
            CG(A, tb, 16);
            CG(B, tb, 24);
        }
        __syncthreads();
    }

    if (wid == 1) out[(size_t)L_DIM * BD + chain] = c;
}

// ---------- launch ----------
extern "C" void kernel_launch(void* const* d_in, const int* in_sizes, int n_in,
                              void* d_out, int out_size, void* d_ws, size_t ws_size,
                              hipStream_t stream) {
    const float* x      = (const float*)d_in[0];
    const float* weight = (const float*)d_in[1];
    const float* wc     = (const float*)d_in[2];
    const float* bias   = (const float*)d_in[3];
    const float* cinit  = (const float*)d_in[4];
    float* out = (float*)d_out;

    // ws layout (bf16 elems): xb[PLANE] | U0|U1|U2 [3*PLANE] | wt[786432]
    ushort_t* ws = (ushort_t*)d_ws;
    ushort_t* xb = ws;
    ushort_t* U  = ws + PLANE;           // 3 contiguous planes
    ushort_t* wt = ws + 4 * PLANE;

    k_convert_x<<<4096, 256, 0, stream>>>((const float4*)x, (ushort4*)xb);
    k_prep_w<<<(N_DIM * K_DIM) / 256, 256, 0, stream>>>(weight, wt);
    k_gemm256<<<1536, 256, 0, stream>>>(xb, wt, bias, U);
    k_scan<<<BD / 64, 128, 0, stream>>>(U, xb, wc, cinit, out);
}

// Round 10
// 269.061 us; speedup vs baseline: 2.2583x; 1.6872x over previous
//
#include <hip/hip_runtime.h>
#include <hip/hip_bf16.h>
#include <stdint.h>

typedef __attribute__((ext_vector_type(4))) float f32x4;
typedef __attribute__((ext_vector_type(8))) short short8;
typedef unsigned int u32;
typedef unsigned short ushort_t;

#define L_DIM 2048
#define B_DIM 32
#define D_DIM 512
#define M_DIM (L_DIM * B_DIM)       // 65536
#define N_DIM (3 * D_DIM)           // 1536
#define K_DIM D_DIM                 // 512
#define BD    (B_DIM * D_DIM)       // 16384
#define PLANE ((size_t)M_DIM * D_DIM)  // 33554432 elems per U plane
#define CHUNK 32
#define NCHUNK (L_DIM / CHUNK)      // 64
#define LOG2E 1.4426950408889634f

// ---------- helpers ----------
__device__ inline ushort_t f2bf(float f) {
    uint32_t u = __float_as_uint(f);
    u += 0x7FFFu + ((u >> 16) & 1u);   // RNE
    return (ushort_t)(u >> 16);
}
__device__ inline float b2f(ushort_t h) {
    return __uint_as_float(((uint32_t)h) << 16);
}
__device__ inline float exp2_hw(float x) {
    float r;
    asm("v_exp_f32 %0, %1" : "=v"(r) : "v"(x));
    return r;
}
__device__ inline void gll16(const ushort_t* g, ushort_t* l) {
    __builtin_amdgcn_global_load_lds(
        (const __attribute__((address_space(1))) u32*)g,
        (__attribute__((address_space(3))) u32*)l,
        16, 0, 0);
}

// ---------- kernel 1: x (f32) -> xb (bf16) ----------
__global__ void k_convert_x(const float4* __restrict__ x, ushort4* __restrict__ xb) {
    int i = blockIdx.x * blockDim.x + threadIdx.x;
    int stride = gridDim.x * blockDim.x;
    const int n4 = M_DIM * D_DIM / 4;   // 8388608
    for (; i < n4; i += stride) {
        float4 v = x[i];
        ushort4 o;
        o.x = f2bf(v.x); o.y = f2bf(v.y); o.z = f2bf(v.z); o.w = f2bf(v.w);
        xb[i] = o;
    }
}

// ---------- kernel 2: weight (D,3D) f32 -> wt [N][K] bf16, gate-deinterleaved ----------
__global__ void k_prep_w(const float* __restrict__ w, ushort_t* __restrict__ wt) {
    int idx = blockIdx.x * blockDim.x + threadIdx.x;
    if (idx >= N_DIM * K_DIM) return;
    int k = idx & 511;
    int n = idx >> 9;
    int dcol = (n & 511) * 3 + (n >> 9);
    wt[idx] = f2bf(w[(size_t)k * N_DIM + dcol]);
}

// ---------- kernel 3: GEMM (round-3 verified) + prescaled gate planes ----------
// U plane 0: u0 (raw).  Planes 1/2: -log2e * (u + bias)  so the scan's sigmoid is
// f = rcp(1 + 2^(u1n + c*fwn)) with fwn = -log2e*fw  (one v_exp, no extra mul).
__global__ __launch_bounds__(256) void k_gemm(
    const ushort_t* __restrict__ Ag,   // [M,K] bf16
    const ushort_t* __restrict__ Wt,   // [N,K] bf16
    const float*    __restrict__ bias, // [2D]
    ushort_t*       __restrict__ U)    // 3 planes of [M,D] bf16
{
    __shared__ ushort_t As[128 * 64];
    __shared__ ushort_t Bs[128 * 64];
    const int tid  = threadIdx.x;
    const int lane = tid & 63;
    const int w    = tid >> 6;
    const int wm   = w >> 1, wn = w & 1;

    // XCD-chunked swizzle: 6144 blocks, 8 XCDs, 768 per XCD (bijective).
    const int i   = blockIdx.x;
    const int nb  = (i & 7) * 768 + (i >> 3);
    const int bx  = nb % 12;             // N tile (innermost -> A reuse)
    const int by  = nb / 12;             // M strip
    const int bn0 = bx * 128;
    const int bm0 = by * 128;

    f32x4 acc[4][4] = {};

    for (int kt = 0; kt < K_DIM / 64; ++kt) {
        if (kt) __syncthreads();
#pragma unroll
        for (int it = 0; it < 4; ++it) {
            int c   = it * 256 + tid;
            int row = c >> 3;
            int cin = (c & 7) ^ (row & 7);
            const ushort_t* ga = Ag + (size_t)(bm0 + row) * K_DIM + kt * 64 + cin * 8;
            const ushort_t* gb = Wt + (size_t)(bn0 + row) * K_DIM + kt * 64 + cin * 8;
            int chunkbase = it * 256 + w * 64;   // wave-uniform
            gll16(ga, As + chunkbase * 8);
            gll16(gb, Bs + chunkbase * 8);
        }
        __syncthreads();
#pragma unroll
        for (int kk = 0; kk < 2; ++kk) {
            short8 af[4], bfr[4];
#pragma unroll
            for (int m = 0; m < 4; ++m) {
                int row  = wm * 64 + m * 16 + (lane & 15);
                int byte = (row * 128 + kk * 64 + ((lane >> 4) * 16)) ^ ((row & 7) << 4);
                af[m] = *(const short8*)((const char*)As + byte);
            }
#pragma unroll
            for (int n = 0; n < 4; ++n) {
                int row  = wn * 64 + n * 16 + (lane & 15);
                int byte = (row * 128 + kk * 64 + ((lane >> 4) * 16)) ^ ((row & 7) << 4);
                bfr[n] = *(const short8*)((const char*)Bs + byte);
            }
#pragma unroll
            for (int m = 0; m < 4; ++m)
#pragma unroll
                for (int n = 0; n < 4; ++n)
                    acc[m][n] = __builtin_amdgcn_mfma_f32_16x16x32_bf16(
                        af[m], bfr[n], acc[m][n], 0, 0, 0);
        }
    }

    const int g  = bn0 >> 9;               // plane (block fully inside one plane)
    const int db = (bn0 & 511) + wn * 64;  // d base in plane
    const float sgn = g ? -LOG2E : 1.0f;   // prescale gate planes
    ushort_t* Up = U + (size_t)g * PLANE;
#pragma unroll
    for (int n = 0; n < 4; ++n) {
        int col = db + n * 16 + (lane & 15);
        float ba = 0.f;
        if (g) ba = bias[(g - 1) * 512 + col];
#pragma unroll
        for (int m = 0; m < 4; ++m) {
            int row0 = bm0 + wm * 64 + m * 16 + ((lane >> 4) * 4);
#pragma unroll
            for (int q = 0; q < 4; ++q) {
                Up[(size_t)(row0 + q) * D_DIM + col] = f2bf((acc[m][n][q] + ba) * sgn);
            }
        }
    }
}

// ---------- kernel 4: role-split scan ----------
// wave 0: producer (gll16 staging of u0,u1n,u2n,x)
// wave 1: serial c-chain ONLY, writes incoming c (cp0) + per-step NEW c (cr)
// waves 2-3: finishers — r from c_prev, h from c_new, parallel over t (lag 1)
__global__ __launch_bounds__(256) void k_scan2(
    const ushort_t* __restrict__ U,    // planes: u0 | u1n | u2n  [t*32+b][d]
    const ushort_t* __restrict__ xb,   // [t*32+b][d]
    const float*    __restrict__ wc,   // weight_c [2D]
    const float*    __restrict__ cin,  // c_init [B,D]
    float*          __restrict__ out)  // h [L,B,D] f32, then c_last [B,D]
{
    __shared__ ushort_t r01[2][2][CHUNK][64];  // u0,u1n ring (16 KB)
    __shared__ ushort_t r23[3][2][CHUNK][64];  // u2n,x ring, 3-deep (24 KB)
    __shared__ float    cr[2][CHUNK][64];      // c_new ring (16 KB)
    __shared__ float    cp0[2][64];            // chunk-incoming c (512 B)

    const int tid  = threadIdx.x;
    const int lane = tid & 63;
    const int wv   = tid >> 6;               // 0 prod, 1 chain, 2-3 finish
    const int cb   = blockIdx.x * 64;        // chain base

    // producer lane mapping (gll16: lane l -> step l>>3, chains (l&7)*8)
    const int srow = lane >> 3;
    const int scol = (lane & 7) * 8;
    const ushort_t* s0 = U + cb + scol;
    const ushort_t* s1 = U + PLANE + cb + scol;
    const ushort_t* s2 = U + 2 * PLANE + cb + scol;
    const ushort_t* s3 = xb + cb + scol;

    const int chain = cb + lane;
    const int d     = chain & 511;
    float fwn = 0.f, c = 0.f, rwn = 0.f;
    if (wv == 1) { fwn = -LOG2E * wc[d]; c = cin[chain]; }
    if (wv >= 2) { rwn = -LOG2E * wc[512 + d]; }
    float* ho = out + chain;

#define PRODUCE(CK)                                                            \
    do {                                                                       \
        const size_t t0_ = (size_t)(CK) * CHUNK + srow;                        \
        const int nb_ = (CK) & 1, nc_ = (CK) % 3;                              \
        _Pragma("unroll")                                                      \
        for (int q = 0; q < 4; ++q) {                                          \
            gll16(s0 + (t0_ + q * 8) * BD, &r01[nb_][0][q * 8][0]);            \
            gll16(s1 + (t0_ + q * 8) * BD, &r01[nb_][1][q * 8][0]);            \
            gll16(s2 + (t0_ + q * 8) * BD, &r23[nc_][0][q * 8][0]);            \
            gll16(s3 + (t0_ + q * 8) * BD, &r23[nc_][1][q * 8][0]);            \
        }                                                                      \
    } while (0)

    if (wv == 0) PRODUCE(0);
    __syncthreads();

    for (int ck = 0; ck <= NCHUNK; ++ck) {
        if (wv == 0) {
            if (ck + 1 < NCHUNK) PRODUCE(ck + 1);
        } else if (wv == 1) {
            if (ck < NCHUNK) {
                const int b = ck & 1;
                cp0[b][lane] = c;            // incoming c for this chunk
#pragma unroll
                for (int s = 0; s < CHUNK; ++s) {
                    float u0  = b2f(r01[b][0][s][lane]);
                    float u1n = b2f(r01[b][1][s][lane]);
                    float f = __builtin_amdgcn_rcpf(
                        1.f + exp2_hw(fmaf(c, fwn, u1n)));
                    c = fmaf(c - u0, f, u0);
                    cr[b][s][lane] = c;
                }
            }
        } else {
            if (ck >= 1) {
                const int fk = ck - 1;
                const int bc = fk & 1, b3 = fk % 3;
                const int sb = (wv - 2) * 16;
                const size_t tb = (size_t)fk * CHUNK;
                // c_prev for first step of this 16-segment
                float cp = (sb == 0) ? cp0[bc][lane] : cr[bc][15][lane];
#pragma unroll
                for (int s2 = 0; s2 < 16; ++s2) {
                    int s = sb + s2;
                    float cc  = cr[bc][s][lane];          // c_new at step s
                    float u2n = b2f(r23[b3][0][s][lane]);
                    float xf  = b2f(r23[b3][1][s][lane]);
                    float r = __builtin_amdgcn_rcpf(
                        1.f + exp2_hw(fmaf(cp, rwn, u2n)));   // r uses c_prev
                    ho[(tb + s) * BD] = fmaf(cc - xf, r, xf); // h uses c_new
                    cp = cc;
                }
            }
        }
        __syncthreads();
    }

    if (wv == 1) out[(size_t)L_DIM * BD + chain] = c;
}

// ---------- launch ----------
extern "C" void kernel_launch(void* const* d_in, const int* in_sizes, int n_in,
                              void* d_out, int out_size, void* d_ws, size_t ws_size,
                              hipStream_t stream) {
    const float* x      = (const float*)d_in[0];
    const float* weight = (const float*)d_in[1];
    const float* wc     = (const float*)d_in[2];
    const float* bias   = (const float*)d_in[3];
    const float* cinit  = (const float*)d_in[4];
    float* out = (float*)d_out;

    // ws layout (bf16 elems): xb[PLANE] | U0|U1n|U2n [3*PLANE] | wt[786432]
    ushort_t* ws = (ushort_t*)d_ws;
    ushort_t* xb = ws;
    ushort_t* U  = ws + PLANE;           // 3 contiguous planes
    ushort_t* wt = ws + 4 * PLANE;

    k_convert_x<<<4096, 256, 0, stream>>>((const float4*)x, (ushort4*)xb);
    k_prep_w<<<(N_DIM * K_DIM) / 256, 256, 0, stream>>>(weight, wt);
    k_gemm<<<6144, 256, 0, stream>>>(xb, wt, bias, U);
    k_scan2<<<BD / 64, 256, 0, stream>>>(U, xb, wc, cinit, out);
}